// Round 7
// baseline (216.455 us; speedup 1.0000x reference)
//
#include <hip/hip_runtime.h>
#include <hip/hip_bf16.h>
#include <stdint.h>

typedef _Float16 f16;
typedef _Float16 f16x8 __attribute__((ext_vector_type(8)));
typedef float f32x4 __attribute__((ext_vector_type(4)));

#define AS1 __attribute__((address_space(1)))
#define AS3 __attribute__((address_space(3)))

// ---------------------------------------------------------------------------
// Transpose + fp32->fp16 convert:  src [R][C] f32  ->  dst [C][R] f16
// ---------------------------------------------------------------------------
__global__ __launch_bounds__(256) void tr_cvt_kernel(
    const float* __restrict__ src, f16* __restrict__ dst, int R, int C)
{
    __shared__ float tile[64][65];
    const int b = blockIdx.z;
    src += (size_t)b * R * C;
    dst += (size_t)b * R * C;
    const int c0 = blockIdx.x * 64;
    const int r0 = blockIdx.y * 64;
    const int t = threadIdx.x;
    {
        const int cc = (t & 15) * 4;
        const int rr = t >> 4;
#pragma unroll
        for (int p = 0; p < 4; ++p) {
            const int r = rr + p * 16;
            const float4 v = *(const float4*)(src + (size_t)(r0 + r) * C + c0 + cc);
            tile[r][cc + 0] = v.x; tile[r][cc + 1] = v.y;
            tile[r][cc + 2] = v.z; tile[r][cc + 3] = v.w;
        }
    }
    __syncthreads();
    {
        const int rq = (t & 15) * 4;
        const int cp = t >> 4;
#pragma unroll
        for (int p = 0; p < 4; ++p) {
            const int c = cp + p * 16;
            ushort4 o;
            f16 h0 = (f16)tile[rq + 0][c];
            f16 h1 = (f16)tile[rq + 1][c];
            f16 h2 = (f16)tile[rq + 2][c];
            f16 h3 = (f16)tile[rq + 3][c];
            o.x = __builtin_bit_cast(unsigned short, h0);
            o.y = __builtin_bit_cast(unsigned short, h1);
            o.z = __builtin_bit_cast(unsigned short, h2);
            o.w = __builtin_bit_cast(unsigned short, h3);
            *(ushort4*)(dst + (size_t)(c0 + c) * R + r0 + rq) = o;
        }
    }
}

// ---------------------------------------------------------------------------
// 8-phase 256x256 GEMM core (m201-style granularity), BK=64.
// LDS per matrix: [2 buf][2 kk][256 rows][32 f16] = 64KB (A) + 64KB (B).
// Per K-tile 4 phases: {stage 1 half-tile (2 gload_lds) ; ds_read 4-8 b128 ;
// vmcnt(4) at P2/P4 only (never 0 mid-loop) ; s_barrier ; lgkmcnt(0) ;
// setprio(1) 16 MFMA setprio(0) ; s_barrier}. Staging 1 tile ahead.
// Swizzle: physical chunk = logical ^ ((row>>1)&3); linear gload_lds dest,
// inverse-swizzled global source; read applies same XOR (rule-21 involution).
// ---------------------------------------------------------------------------
__device__ __forceinline__ void stage_half(
    const f16* __restrict__ gsrc, int ld, f16* lds, int tid, int r0, int lk0)
{
    const f16* s0 = gsrc + (size_t)r0 * ld + lk0 * 8;
    __builtin_amdgcn_global_load_lds((const AS1 uint32_t*)s0,
        (AS3 uint32_t*)(lds + tid * 8), 16, 0, 0);
    const f16* s1 = s0 + (size_t)128 * ld;
    __builtin_amdgcn_global_load_lds((const AS1 uint32_t*)s1,
        (AS3 uint32_t*)(lds + (512 + tid) * 8), 16, 0, 0);
}

template <int R0>
__device__ __forceinline__ void mfma16(
    f32x4 (&acc)[8][4], const f16x8 (&af)[4], const f16x8 (&bf)[4])
{
    __builtin_amdgcn_s_setprio(1);
#pragma unroll
    for (int i = 0; i < 4; ++i)
#pragma unroll
        for (int j = 0; j < 4; ++j)
            acc[R0 + i][j] = __builtin_amdgcn_mfma_f32_16x16x32_f16(
                af[i], bf[j], acc[R0 + i][j], 0, 0, 0);
    __builtin_amdgcn_s_setprio(0);
}

template <int T>
__device__ __forceinline__ void gemm256_8p(
    const f16* __restrict__ A, int lda,
    const f16* __restrict__ Bt, int ldb,
    f16* LA, f16* LB, f32x4 (&acc)[8][4], int tid)
{
    const int lane = tid & 63, w = tid >> 6;
    const int wr = w >> 2, wc = w & 3;
    const int cl = lane & 15, kg = lane >> 4;
    const int loff = cl * 32 + ((kg ^ ((cl >> 1) & 3)) * 8);  // per-lane, const
    const int abase = wr * 128 * 32;
    const int bbase = wc * 64 * 32;
    // staging source mapping (linear dest chunk n=(p*512+tid) -> row,chunk)
    const int r0 = tid >> 2;
    const int lk0 = (tid & 3) ^ ((r0 >> 1) & 3);  // same for both loads

    // prologue: stage tile 0 halves in order Ak0,Bk0,Ak1,Bk1; drain first two
    stage_half(A, lda, LA, tid, r0, lk0);
    stage_half(Bt, ldb, LB, tid, r0, lk0);
    stage_half(A + 32, lda, LA + 8192, tid, r0, lk0);
    stage_half(Bt + 32, ldb, LB + 8192, tid, r0, lk0);
    asm volatile("s_waitcnt vmcnt(4)" ::: "memory");
    __builtin_amdgcn_s_barrier();

#pragma unroll 1
    for (int t = 0; t < T; ++t) {
        const int d = t & 1;
        const int nt = (t + 1 < T) ? (t + 1) : 0;   // wrap: harmless re-stage
        const f16* An = A + (size_t)nt * 64;
        const f16* Bn = Bt + (size_t)nt * 64;
        f16* LAs = LA + (d ^ 1) * 16384;
        f16* LBs = LB + (d ^ 1) * 16384;
        const f16* LAc = LA + d * 16384;
        const f16* LBc = LB + d * 16384;
        f16x8 af[4], bf[4];

        // ---- P1: kk0, rows mh0 ----
        stage_half(An, lda, LAs, tid, r0, lk0);               // Ak0(t+1)
#pragma unroll
        for (int i = 0; i < 4; ++i) af[i] = *(const f16x8*)&LAc[abase + i * 512 + loff];
#pragma unroll
        for (int j = 0; j < 4; ++j) bf[j] = *(const f16x8*)&LBc[bbase + j * 512 + loff];
        __builtin_amdgcn_s_barrier();
        asm volatile("s_waitcnt lgkmcnt(0)" ::: "memory");
        __builtin_amdgcn_sched_barrier(0);
        mfma16<0>(acc, af, bf);
        __builtin_amdgcn_s_barrier();

        // ---- P2: kk0, rows mh1 ----
        stage_half(Bn, ldb, LBs, tid, r0, lk0);               // Bk0(t+1)
#pragma unroll
        for (int i = 0; i < 4; ++i) af[i] = *(const f16x8*)&LAc[abase + 2048 + i * 512 + loff];
        asm volatile("s_waitcnt vmcnt(4)" ::: "memory");      // drains Ak1,Bk1(t)
        __builtin_amdgcn_s_barrier();
        asm volatile("s_waitcnt lgkmcnt(0)" ::: "memory");
        __builtin_amdgcn_sched_barrier(0);
        mfma16<4>(acc, af, bf);
        __builtin_amdgcn_s_barrier();

        // ---- P3: kk1, rows mh0 ----
        stage_half(An + 32, lda, LAs + 8192, tid, r0, lk0);   // Ak1(t+1)
#pragma unroll
        for (int i = 0; i < 4; ++i) af[i] = *(const f16x8*)&LAc[8192 + abase + i * 512 + loff];
#pragma unroll
        for (int j = 0; j < 4; ++j) bf[j] = *(const f16x8*)&LBc[8192 + bbase + j * 512 + loff];
        __builtin_amdgcn_s_barrier();
        asm volatile("s_waitcnt lgkmcnt(0)" ::: "memory");
        __builtin_amdgcn_sched_barrier(0);
        mfma16<0>(acc, af, bf);
        __builtin_amdgcn_s_barrier();

        // ---- P4: kk1, rows mh1 ----
        stage_half(Bn + 32, ldb, LBs + 8192, tid, r0, lk0);   // Bk1(t+1)
#pragma unroll
        for (int i = 0; i < 4; ++i) af[i] = *(const f16x8*)&LAc[8192 + abase + 2048 + i * 512 + loff];
        asm volatile("s_waitcnt vmcnt(4)" ::: "memory");      // drains Ak0,Bk0(t+1)
        __builtin_amdgcn_s_barrier();
        asm volatile("s_waitcnt lgkmcnt(0)" ::: "memory");
        __builtin_amdgcn_sched_barrier(0);
        mfma16<4>(acc, af, bf);
        __builtin_amdgcn_s_barrier();
    }
}

// ---------------------------------------------------------------------------
// K1: Gp[s][b] = xT_b[:, s*2048 : +2048] self-product (full G, split-K=2).
// grid: 256 blocks (16 tiles x 8 batch x 2 splits), XCD-chunked swizzle.
// ---------------------------------------------------------------------------
__global__ __launch_bounds__(512, 2) void gemm_syk256(
    const f16* __restrict__ xT, f16* __restrict__ Gp)
{
    __shared__ f16 LA[2 * 2 * 8192];
    __shared__ f16 LB[2 * 2 * 8192];
    const int orig = blockIdx.x;
    const int l = (orig & 7) * 32 + (orig >> 3);   // 256 = 8*32, bijective
    const int tile = l & 15, b = (l >> 4) & 7, s = l >> 7;
    const int ti = tile >> 2, tj = tile & 3;

    const f16* base = xT + (size_t)b * (1024 * 4096) + (size_t)s * 2048;
    const f16* A  = base + (size_t)ti * 256 * 4096;
    const f16* Bt = base + (size_t)tj * 256 * 4096;

    f32x4 acc[8][4];
#pragma unroll
    for (int i = 0; i < 8; ++i)
#pragma unroll
        for (int j = 0; j < 4; ++j) acc[i][j] = f32x4{0.f, 0.f, 0.f, 0.f};

    gemm256_8p<32>(A, 4096, Bt, 4096, LA, LB, acc, threadIdx.x);

    f16* out = Gp + ((size_t)s * 8 + b) * 1048576;
    const int lane = threadIdx.x & 63, w = threadIdx.x >> 6;
    const int wr = w >> 2, wc = w & 3;
    const int cl = lane & 15, rg = lane >> 4;
#pragma unroll
    for (int i = 0; i < 8; ++i)
#pragma unroll
        for (int j = 0; j < 4; ++j)
#pragma unroll
            for (int q = 0; q < 4; ++q) {
                const int row = ti * 256 + wr * 128 + i * 16 + rg * 4 + q;
                const int col = tj * 256 + wc * 64 + j * 16 + cl;
                out[(size_t)row * 1024 + col] = (f16)acc[i][j][q];
            }
}

// ---------------------------------------------------------------------------
// reduce: G = Gp[0] + Gp[1]  (elementwise, f32 accumulate)
// ---------------------------------------------------------------------------
__global__ __launch_bounds__(256) void reduce_sum(
    const f16* __restrict__ Gp, f16* __restrict__ G)
{
    const size_t i = ((size_t)blockIdx.x * 256 + threadIdx.x) * 8;
    const f16x8 a = *(const f16x8*)(Gp + i);
    const f16x8 c = *(const f16x8*)(Gp + 8388608 + i);
    f16x8 o;
#pragma unroll
    for (int j = 0; j < 8; ++j) o[j] = (f16)((float)a[j] + (float)c[j]);
    *(f16x8*)(G + i) = o;
}

// ---------------------------------------------------------------------------
// K2 fused (256^2, 8-phase): UW2[b] = [Wq^T G_b ; Wv^T G_b], K=1024.
// grid: 256 blocks (4 N x 8 M x 8 batch), XCD-chunked swizzle.
// ---------------------------------------------------------------------------
__global__ __launch_bounds__(512, 2) void gemm_qv256(
    const f16* __restrict__ WqkvT, const f16* __restrict__ G,
    f16* __restrict__ UW2)
{
    __shared__ f16 LA[2 * 2 * 8192];
    __shared__ f16 LB[2 * 2 * 8192];
    const int orig = blockIdx.x;
    const int l = (orig & 7) * 32 + (orig >> 3);
    const int bx = l & 3, by = (l >> 2) & 7, b = l >> 5;
    const int arow = (by < 4) ? by * 256 : 2048 + (by - 4) * 256;  // skip Wk

    const f16* A  = WqkvT + (size_t)arow * 1024;
    const f16* Bt = G + (size_t)b * 1048576 + (size_t)bx * 256 * 1024;

    f32x4 acc[8][4];
#pragma unroll
    for (int i = 0; i < 8; ++i)
#pragma unroll
        for (int j = 0; j < 4; ++j) acc[i][j] = f32x4{0.f, 0.f, 0.f, 0.f};

    gemm256_8p<16>(A, 1024, Bt, 1024, LA, LB, acc, threadIdx.x);

    f16* C = UW2 + (size_t)b * 2097152;
    const int lane = threadIdx.x & 63, w = threadIdx.x >> 6;
    const int wr = w >> 2, wc = w & 3;
    const int cl = lane & 15, rg = lane >> 4;
#pragma unroll
    for (int i = 0; i < 8; ++i)
#pragma unroll
        for (int j = 0; j < 4; ++j) {
            const int cc = bx * 256 + wc * 64 + j * 16 + cl;
#pragma unroll
            for (int q = 0; q < 4; ++q) {
                const int rr = by * 256 + wr * 128 + i * 16 + rg * 4 + q;
                C[(size_t)rr * 1024 + cc] = (f16)acc[i][j][q];
            }
        }
}

// ---------------------------------------------------------------------------
// Legacy 128x128 body (used by gemm_out only)
// ---------------------------------------------------------------------------
__device__ __forceinline__ void gemm_body(
    const f16* __restrict__ A, const f16* __restrict__ Bt,
    int lda, int ldb, int K, f16* As, f16* Bs,
    f32x4 (&acc)[4][4], int tid)
{
    const int lane = tid & 63, w = tid >> 6;
    const int wr = w >> 1, wc = w & 1;
    const int lrow = lane >> 3;
    const int lcol = (lane & 7) * 8;
    for (int k0 = 0; k0 < K; k0 += 64) {
#pragma unroll
        for (int p = 0; p < 4; ++p) {
            const f16* sa = A + (size_t)(p * 32 + w * 8 + lrow) * lda + k0 + lcol;
            __builtin_amdgcn_global_load_lds(
                (const AS1 uint32_t*)sa,
                (AS3 uint32_t*)((char*)As + p * 4096 + w * 1024), 16, 0, 0);
            const f16* sb = Bt + (size_t)(p * 32 + w * 8 + lrow) * ldb + k0 + lcol;
            __builtin_amdgcn_global_load_lds(
                (const AS1 uint32_t*)sb,
                (AS3 uint32_t*)((char*)Bs + p * 4096 + w * 1024), 16, 0, 0);
        }
        __syncthreads();
#pragma unroll
        for (int kk = 0; kk < 2; ++kk) {
            f16x8 af[4], bfr[4];
#pragma unroll
            for (int i = 0; i < 4; ++i)
                af[i] = *(const f16x8*)&As[(wr * 64 + i * 16 + (lane & 15)) * 64 + kk * 32 + (lane >> 4) * 8];
#pragma unroll
            for (int j = 0; j < 4; ++j)
                bfr[j] = *(const f16x8*)&Bs[(wc * 64 + j * 16 + (lane & 15)) * 64 + kk * 32 + (lane >> 4) * 8];
#pragma unroll
            for (int i = 0; i < 4; ++i)
#pragma unroll
                for (int j = 0; j < 4; ++j)
                    acc[i][j] = __builtin_amdgcn_mfma_f32_16x16x32_f16(af[i], bfr[j], acc[i][j], 0, 0, 0);
        }
        __syncthreads();
    }
}

// ---------------------------------------------------------------------------
// bias_init: d_out[512][1024] = bias row-broadcast
// ---------------------------------------------------------------------------
__global__ __launch_bounds__(256) void bias_init(
    const float* __restrict__ bias, float* __restrict__ out)
{
    const int idx = blockIdx.x * 1024 + threadIdx.x * 4;
    const float4 bv = *(const float4*)(bias + (idx & 1023));
    *(float4*)(out + idx) = bv;
}

// ---------------------------------------------------------------------------
// K4: d_out += A * Bt^T, split-K=2 via f32 atomics. grid (8,4,2)
// ---------------------------------------------------------------------------
__global__ __launch_bounds__(256) void gemm_out(
    const f16* __restrict__ A, const f16* __restrict__ Bt,
    float* __restrict__ Cout)
{
    __shared__ f16 As[128 * 64];
    __shared__ f16 Bs[128 * 64];
    const int tn0 = blockIdx.x * 128;
    const int tm0 = blockIdx.y * 128;
    const int s = blockIdx.z;
    f32x4 acc[4][4];
#pragma unroll
    for (int i = 0; i < 4; ++i)
#pragma unroll
        for (int j = 0; j < 4; ++j) acc[i][j] = f32x4{0.f, 0.f, 0.f, 0.f};

    gemm_body(A + (size_t)tm0 * 1024 + s * 512,
              Bt + (size_t)tn0 * 1024 + s * 512, 1024, 1024, 512,
              As, Bs, acc, threadIdx.x);

    const int lane = threadIdx.x & 63, w = threadIdx.x >> 6;
    const int wr = w >> 1, wc = w & 1;
    const int cl = lane & 15, rg = lane >> 4;
#pragma unroll
    for (int i = 0; i < 4; ++i)
#pragma unroll
        for (int j = 0; j < 4; ++j) {
            const int cc = tn0 + wc * 64 + j * 16 + cl;
#pragma unroll
            for (int q = 0; q < 4; ++q) {
                const int rr = tm0 + wr * 64 + i * 16 + rg * 4 + q;
                atomicAdd(&Cout[(size_t)rr * 1024 + cc], acc[i][j][q]);
            }
        }
}

// ---------------------------------------------------------------------------
// Per (b,h): dots = U_h * Wk_h^T, vv = W2_h * Wv2_h^T  (64x64, K=1024),
// softmax(dots*0.125), out = attn @ vv -> O (f16)
// grid: (16 heads, 8 batches), block 512 (8 waves)
// ---------------------------------------------------------------------------
__global__ __launch_bounds__(512) void attn_small(
    const f16* __restrict__ UW2, const f16* __restrict__ WqkvT,
    f16* __restrict__ O)
{
    __shared__ float dots[64][66];
    __shared__ float vv[64][66];
    const int h = blockIdx.x, b = blockIdx.y;
    const int tid = threadIdx.x, lane = tid & 63, w = tid >> 6;
    const int isVV = w >> 2;
    const int kq = w & 3;

    const f16* Arows = UW2 + (size_t)b * (2048 * 1024)
                           + (size_t)isVV * (1024 * 1024) + (size_t)h * 64 * 1024;
    const f16* Brows = WqkvT + (size_t)(isVV ? 3072 : 1024) * 1024 + (size_t)h * 64 * 1024;

    f32x4 acc[4][4];
#pragma unroll
    for (int i = 0; i < 4; ++i)
#pragma unroll
        for (int j = 0; j < 4; ++j) acc[i][j] = f32x4{0.f, 0.f, 0.f, 0.f};

    const int cl = lane & 15, kg = lane >> 4;
    for (int ks = 0; ks < 8; ++ks) {
        const int k0 = kq * 256 + ks * 32 + kg * 8;
        f16x8 af[4], bfr[4];
#pragma unroll
        for (int i = 0; i < 4; ++i)
            af[i] = *(const f16x8*)(Arows + (size_t)(i * 16 + cl) * 1024 + k0);
#pragma unroll
        for (int j = 0; j < 4; ++j)
            bfr[j] = *(const f16x8*)(Brows + (size_t)(j * 16 + cl) * 1024 + k0);
#pragma unroll
        for (int i = 0; i < 4; ++i)
#pragma unroll
            for (int j = 0; j < 4; ++j)
                acc[i][j] = __builtin_amdgcn_mfma_f32_16x16x32_f16(af[i], bfr[j], acc[i][j], 0, 0, 0);
    }

    float (*dst)[66] = isVV ? vv : dots;
#pragma unroll
    for (int r = 0; r < 4; ++r) {
        if (kq == r) {
            if (r == 0) {
#pragma unroll
                for (int i = 0; i < 4; ++i)
#pragma unroll
                    for (int j = 0; j < 4; ++j)
#pragma unroll
                        for (int q = 0; q < 4; ++q)
                            dst[i * 16 + kg * 4 + q][j * 16 + cl] = acc[i][j][q];
            } else {
#pragma unroll
                for (int i = 0; i < 4; ++i)
#pragma unroll
                    for (int j = 0; j < 4; ++j)
#pragma unroll
                        for (int q = 0; q < 4; ++q)
                            dst[i * 16 + kg * 4 + q][j * 16 + cl] += acc[i][j][q];
            }
        }
        __syncthreads();
    }

    if (tid < 64) {
        const int r = tid;
        float mx = -1e30f;
        for (int e = 0; e < 64; ++e) {
            const float v = dots[r][e] * 0.125f;
            dots[r][e] = v;
            mx = fmaxf(mx, v);
        }
        float s = 0.f;
        for (int e = 0; e < 64; ++e) {
            const float v = __expf(dots[r][e] - mx);
            dots[r][e] = v;
            s += v;
        }
        const float inv = 1.f / s;
        for (int e = 0; e < 64; ++e) dots[r][e] *= inv;
    }
    __syncthreads();

    {
        const int r = tid >> 3, f0 = (tid & 7) * 8;
        float o[8];
#pragma unroll
        for (int i = 0; i < 8; ++i) o[i] = 0.f;
        for (int e = 0; e < 64; ++e) {
            const float a = dots[r][e];
#pragma unroll
            for (int i = 0; i < 8; ++i) o[i] += a * vv[e][f0 + i];
        }
        f16* Od = O + (size_t)b * 64 * 1024 + (size_t)r * 1024 + h * 64 + f0;
#pragma unroll
        for (int i = 0; i < 8; ++i) Od[i] = (f16)o[i];
    }
}

// ---------------------------------------------------------------------------
extern "C" void kernel_launch(void* const* d_in, const int* in_sizes, int n_in,
                              void* d_out, int out_size, void* d_ws, size_t ws_size,
                              hipStream_t stream)
{
    const float* x    = (const float*)d_in[0];  // [8][4096][1024]
    const float* Wqkv = (const float*)d_in[1];  // [1024][4096]
    const float* Wout = (const float*)d_in[2];  // [1024][1024]
    const float* bout = (const float*)d_in[3];  // [1024]

    char* ws = (char*)d_ws;
    f16* xT    = (f16*)(ws + 0);           // [8][1024][4096]   67108864 B
    f16* WqkvT = (f16*)(ws + 67108864);    // [4096][1024]       8388608 B
    f16* WoutT = (f16*)(ws + 75497472);    // [1024][1024]       2097152 B
    f16* G     = (f16*)(ws + 77594624);    // [8][1024][1024]   16777216 B
    f16* Gp    = (f16*)(ws + 94371840);    // [2][8][1024][1024] 33554432 B
    f16* UW2   = (f16*)(ws + 94371840);    // union w/ Gp (qv runs after reduce)
    f16* O     = (f16*)(ws + 127926272);   // [8][64][1024]      1048576 B

    tr_cvt_kernel<<<dim3(16, 64, 8), 256, 0, stream>>>(x, xT, 4096, 1024);
    tr_cvt_kernel<<<dim3(64, 16, 1), 256, 0, stream>>>(Wqkv, WqkvT, 1024, 4096);
    tr_cvt_kernel<<<dim3(16, 16, 1), 256, 0, stream>>>(Wout, WoutT, 1024, 1024);

    // K1: full-G split-K=2, 256^2 tiles, 8-phase pipelined
    gemm_syk256<<<256, 512, 0, stream>>>(xT, Gp);
    // G = Gp0 + Gp1
    reduce_sum<<<4096, 256, 0, stream>>>(Gp, G);
    // K2 fused: UW2 = [Wq^T G ; Wv^T G], 8-phase pipelined
    gemm_qv256<<<256, 512, 0, stream>>>(WqkvT, G, UW2);
    // K3: per (b,h) small attention
    attn_small<<<dim3(16, 8), 512, 0, stream>>>(UW2, WqkvT, O);
    // K4: out = bias ; out += O @ WoutT^T (split-K=2, f32 atomics)
    bias_init<<<512, 256, 0, stream>>>(bout, (float*)d_out);
    gemm_out<<<dim3(8, 4, 2), 256, 0, stream>>>(O, WoutT, (float*)d_out);
}

// Round 8
// 204.153 us; speedup vs baseline: 1.0603x; 1.0603x over previous
//
#include <hip/hip_runtime.h>
#include <hip/hip_bf16.h>
#include <stdint.h>

typedef _Float16 f16;
typedef _Float16 f16x8 __attribute__((ext_vector_type(8)));
typedef float f32x4 __attribute__((ext_vector_type(4)));

#define AS1 __attribute__((address_space(1)))
#define AS3 __attribute__((address_space(3)))

// ---------------------------------------------------------------------------
// Transpose + fp32->fp16 convert:  src [R][C] f32  ->  dst [C][R] f16
// ---------------------------------------------------------------------------
__global__ __launch_bounds__(256) void tr_cvt_kernel(
    const float* __restrict__ src, f16* __restrict__ dst, int R, int C)
{
    __shared__ float tile[64][65];
    const int b = blockIdx.z;
    src += (size_t)b * R * C;
    dst += (size_t)b * R * C;
    const int c0 = blockIdx.x * 64;
    const int r0 = blockIdx.y * 64;
    const int t = threadIdx.x;
    {
        const int cc = (t & 15) * 4;
        const int rr = t >> 4;
#pragma unroll
        for (int p = 0; p < 4; ++p) {
            const int r = rr + p * 16;
            const float4 v = *(const float4*)(src + (size_t)(r0 + r) * C + c0 + cc);
            tile[r][cc + 0] = v.x; tile[r][cc + 1] = v.y;
            tile[r][cc + 2] = v.z; tile[r][cc + 3] = v.w;
        }
    }
    __syncthreads();
    {
        const int rq = (t & 15) * 4;
        const int cp = t >> 4;
#pragma unroll
        for (int p = 0; p < 4; ++p) {
            const int c = cp + p * 16;
            ushort4 o;
            f16 h0 = (f16)tile[rq + 0][c];
            f16 h1 = (f16)tile[rq + 1][c];
            f16 h2 = (f16)tile[rq + 2][c];
            f16 h3 = (f16)tile[rq + 3][c];
            o.x = __builtin_bit_cast(unsigned short, h0);
            o.y = __builtin_bit_cast(unsigned short, h1);
            o.z = __builtin_bit_cast(unsigned short, h2);
            o.w = __builtin_bit_cast(unsigned short, h3);
            *(ushort4*)(dst + (size_t)(c0 + c) * R + r0 + rq) = o;
        }
    }
}

// ---------------------------------------------------------------------------
// 256x256-tile, BK=64, 512-thread (8-wave, 2x4) GEMM core — single-barrier
// 2-phase (m230-V0 recipe): per K-step {stage(t+1) ; ds_read(cur) ;
// setprio(1) MFMA setprio(0) ; vmcnt(0) ; s_barrier}. Double-buffered LDS
// (2x32KB per matrix). Chunk-XOR swizzle: LDS linear dest, inverse-swizzled
// global source, read applies same XOR (rule-21 involution, XOR by row&7).
// ---------------------------------------------------------------------------
__device__ __forceinline__ void stage256(
    const f16* __restrict__ src, int ld, char* ldsbase, int tid)
{
    const int lane = tid & 63;
    const int gch = ((lane & 7) ^ (lane >> 3)) * 8;   // inverse-swizzled source
    const int rowl = tid >> 3;                        // 0..63 (w*8 + lane>>3)
    const int wbase = (tid >> 3) & ~7;                // wave-uniform: w*8
#pragma unroll
    for (int p = 0; p < 4; ++p) {
        const f16* s = src + (size_t)(p * 64 + rowl) * ld + gch;
        __builtin_amdgcn_global_load_lds(
            (const AS1 uint32_t*)s,
            (AS3 uint32_t*)(ldsbase + (p * 64 + wbase) * 128), 16, 0, 0);
    }
}

__device__ __forceinline__ void gemm256_core(
    const f16* __restrict__ A, const f16* __restrict__ Bt,
    int lda, int ldb, int nsteps,
    f16* As, f16* Bs, f32x4 (&acc)[8][4], int tid)
{
    const int lane = tid & 63, w = tid >> 6;
    const int wr = w >> 2, wc = w & 3;
    const int cl = lane & 15, kg = lane >> 4, b7 = lane & 7;

    // prologue: stage step 0 into buffer 0, drain, sync
    stage256(A, lda, (char*)As, tid);
    stage256(Bt, ldb, (char*)Bs, tid);
    asm volatile("s_waitcnt vmcnt(0)" ::: "memory");
    __builtin_amdgcn_s_barrier();

#pragma unroll 1
    for (int t = 0; t < nsteps; ++t) {
        const int cur = t & 1;
        if (t + 1 < nsteps) {
            const int k0 = (t + 1) * 64;
            stage256(A + k0, lda, (char*)As + (cur ^ 1) * 32768, tid);
            stage256(Bt + k0, ldb, (char*)Bs + (cur ^ 1) * 32768, tid);
        }
        const f16* Ab = As + cur * 16384;
        const f16* Bb = Bs + cur * 16384;
#pragma unroll
        for (int kk = 0; kk < 2; ++kk) {
            const int ch = (kk * 4 + kg) ^ b7;   // swizzled 16B chunk
            f16x8 af[8], bf[4];
#pragma unroll
            for (int i = 0; i < 8; ++i)
                af[i] = *(const f16x8*)&Ab[(wr * 128 + i * 16 + cl) * 64 + ch * 8];
#pragma unroll
            for (int j = 0; j < 4; ++j)
                bf[j] = *(const f16x8*)&Bb[(wc * 64 + j * 16 + cl) * 64 + ch * 8];
            __builtin_amdgcn_s_setprio(1);
#pragma unroll
            for (int i = 0; i < 8; ++i)
#pragma unroll
                for (int j = 0; j < 4; ++j)
                    acc[i][j] = __builtin_amdgcn_mfma_f32_16x16x32_f16(af[i], bf[j], acc[i][j], 0, 0, 0);
            __builtin_amdgcn_s_setprio(0);
        }
        asm volatile("s_waitcnt vmcnt(0)" ::: "memory");  // t+1 stages landed
        __builtin_amdgcn_s_barrier();                     // single barrier/step
    }
}

// ---------------------------------------------------------------------------
// K1: Gp[s][b] = xT_b[:, s*2048 : +2048] self-product (full G, split-K=2).
// grid: 256 blocks (16 tiles x 8 batch x 2 splits), XCD-chunked swizzle.
// ---------------------------------------------------------------------------
__global__ __launch_bounds__(512, 2) void gemm_syk256(
    const f16* __restrict__ xT, f16* __restrict__ Gp)
{
    __shared__ f16 As[2 * 256 * 64];
    __shared__ f16 Bs[2 * 256 * 64];
    const int orig = blockIdx.x;
    const int l = (orig & 7) * 32 + (orig >> 3);   // 256 = 8*32, bijective
    const int tile = l & 15, b = (l >> 4) & 7, s = l >> 7;
    const int ti = tile >> 2, tj = tile & 3;

    const f16* base = xT + (size_t)b * (1024 * 4096) + (size_t)s * 2048;
    const f16* A  = base + (size_t)ti * 256 * 4096;
    const f16* Bt = base + (size_t)tj * 256 * 4096;

    f32x4 acc[8][4];
#pragma unroll
    for (int i = 0; i < 8; ++i)
#pragma unroll
        for (int j = 0; j < 4; ++j) acc[i][j] = f32x4{0.f, 0.f, 0.f, 0.f};

    gemm256_core(A, Bt, 4096, 4096, 32, As, Bs, acc, threadIdx.x);

    f16* out = Gp + ((size_t)s * 8 + b) * 1048576;
    const int lane = threadIdx.x & 63, w = threadIdx.x >> 6;
    const int wr = w >> 2, wc = w & 3;
    const int cl = lane & 15, rg = lane >> 4;
#pragma unroll
    for (int i = 0; i < 8; ++i)
#pragma unroll
        for (int j = 0; j < 4; ++j)
#pragma unroll
            for (int q = 0; q < 4; ++q) {
                const int row = ti * 256 + wr * 128 + i * 16 + rg * 4 + q;
                const int col = tj * 256 + wc * 64 + j * 16 + cl;
                out[(size_t)row * 1024 + col] = (f16)acc[i][j][q];
            }
}

// ---------------------------------------------------------------------------
// reduce: G = Gp[0] + Gp[1]  (elementwise, f32 accumulate)
// ---------------------------------------------------------------------------
__global__ __launch_bounds__(256) void reduce_sum(
    const f16* __restrict__ Gp, f16* __restrict__ G)
{
    const size_t i = ((size_t)blockIdx.x * 256 + threadIdx.x) * 8;
    const f16x8 a = *(const f16x8*)(Gp + i);
    const f16x8 c = *(const f16x8*)(Gp + 8388608 + i);
    f16x8 o;
#pragma unroll
    for (int j = 0; j < 8; ++j) o[j] = (f16)((float)a[j] + (float)c[j]);
    *(f16x8*)(G + i) = o;
}

// ---------------------------------------------------------------------------
// K2 fused (256^2): UW2[b] = [Wq^T G_b ; Wv^T G_b], K=1024.
// grid: 256 blocks (4 N x 8 M x 8 batch), XCD-chunked swizzle.
// ---------------------------------------------------------------------------
__global__ __launch_bounds__(512, 2) void gemm_qv256(
    const f16* __restrict__ WqkvT, const f16* __restrict__ G,
    f16* __restrict__ UW2)
{
    __shared__ f16 As[2 * 256 * 64];
    __shared__ f16 Bs[2 * 256 * 64];
    const int orig = blockIdx.x;
    const int l = (orig & 7) * 32 + (orig >> 3);
    const int bx = l & 3, by = (l >> 2) & 7, b = l >> 5;
    const int arow = (by < 4) ? by * 256 : 2048 + (by - 4) * 256;  // skip Wk

    const f16* A  = WqkvT + (size_t)arow * 1024;
    const f16* Bt = G + (size_t)b * 1048576 + (size_t)bx * 256 * 1024;

    f32x4 acc[8][4];
#pragma unroll
    for (int i = 0; i < 8; ++i)
#pragma unroll
        for (int j = 0; j < 4; ++j) acc[i][j] = f32x4{0.f, 0.f, 0.f, 0.f};

    gemm256_core(A, Bt, 1024, 1024, 16, As, Bs, acc, threadIdx.x);

    f16* C = UW2 + (size_t)b * 2097152;
    const int lane = threadIdx.x & 63, w = threadIdx.x >> 6;
    const int wr = w >> 2, wc = w & 3;
    const int cl = lane & 15, rg = lane >> 4;
#pragma unroll
    for (int i = 0; i < 8; ++i)
#pragma unroll
        for (int j = 0; j < 4; ++j) {
            const int cc = bx * 256 + wc * 64 + j * 16 + cl;
#pragma unroll
            for (int q = 0; q < 4; ++q) {
                const int rr = by * 256 + wr * 128 + i * 16 + rg * 4 + q;
                C[(size_t)rr * 1024 + cc] = (f16)acc[i][j][q];
            }
        }
}

// ---------------------------------------------------------------------------
// Legacy 128x128 body (used by gemm_out only)
// ---------------------------------------------------------------------------
__device__ __forceinline__ void gemm_body(
    const f16* __restrict__ A, const f16* __restrict__ Bt,
    int lda, int ldb, int K, f16* As, f16* Bs,
    f32x4 (&acc)[4][4], int tid)
{
    const int lane = tid & 63, w = tid >> 6;
    const int wr = w >> 1, wc = w & 1;
    const int lrow = lane >> 3;
    const int lcol = (lane & 7) * 8;
    for (int k0 = 0; k0 < K; k0 += 64) {
#pragma unroll
        for (int p = 0; p < 4; ++p) {
            const f16* sa = A + (size_t)(p * 32 + w * 8 + lrow) * lda + k0 + lcol;
            __builtin_amdgcn_global_load_lds(
                (const AS1 uint32_t*)sa,
                (AS3 uint32_t*)((char*)As + p * 4096 + w * 1024), 16, 0, 0);
            const f16* sb = Bt + (size_t)(p * 32 + w * 8 + lrow) * ldb + k0 + lcol;
            __builtin_amdgcn_global_load_lds(
                (const AS1 uint32_t*)sb,
                (AS3 uint32_t*)((char*)Bs + p * 4096 + w * 1024), 16, 0, 0);
        }
        __syncthreads();
#pragma unroll
        for (int kk = 0; kk < 2; ++kk) {
            f16x8 af[4], bfr[4];
#pragma unroll
            for (int i = 0; i < 4; ++i)
                af[i] = *(const f16x8*)&As[(wr * 64 + i * 16 + (lane & 15)) * 64 + kk * 32 + (lane >> 4) * 8];
#pragma unroll
            for (int j = 0; j < 4; ++j)
                bfr[j] = *(const f16x8*)&Bs[(wc * 64 + j * 16 + (lane & 15)) * 64 + kk * 32 + (lane >> 4) * 8];
#pragma unroll
            for (int i = 0; i < 4; ++i)
#pragma unroll
                for (int j = 0; j < 4; ++j)
                    acc[i][j] = __builtin_amdgcn_mfma_f32_16x16x32_f16(af[i], bfr[j], acc[i][j], 0, 0, 0);
        }
        __syncthreads();
    }
}

// ---------------------------------------------------------------------------
// K4: d_out = O @ WoutT^T + bias.  grid (8,4), block 256. K=1024.
// ---------------------------------------------------------------------------
__global__ __launch_bounds__(256) void gemm_out(
    const f16* __restrict__ A, const f16* __restrict__ Bt,
    const float* __restrict__ bias, float* __restrict__ Cout)
{
    __shared__ f16 As[128 * 64];
    __shared__ f16 Bs[128 * 64];
    const int tn0 = blockIdx.x * 128;
    const int tm0 = blockIdx.y * 128;
    f32x4 acc[4][4];
#pragma unroll
    for (int i = 0; i < 4; ++i)
#pragma unroll
        for (int j = 0; j < 4; ++j) acc[i][j] = f32x4{0.f, 0.f, 0.f, 0.f};

    gemm_body(A + (size_t)tm0 * 1024, Bt + (size_t)tn0 * 1024,
              1024, 1024, 1024, As, Bs, acc, threadIdx.x);

    const int lane = threadIdx.x & 63, w = threadIdx.x >> 6;
    const int wr = w >> 1, wc = w & 1;
    const int cl = lane & 15, rg = lane >> 4;
#pragma unroll
    for (int i = 0; i < 4; ++i)
#pragma unroll
        for (int j = 0; j < 4; ++j) {
            const int cc = tn0 + wc * 64 + j * 16 + cl;
            const float bv = bias[cc];
#pragma unroll
            for (int q = 0; q < 4; ++q) {
                const int rr = tm0 + wr * 64 + i * 16 + rg * 4 + q;
                Cout[(size_t)rr * 1024 + cc] = acc[i][j][q] + bv;
            }
        }
}

// ---------------------------------------------------------------------------
// Per (b,h): dots = U_h * Wk_h^T, vv = W2_h * Wv2_h^T  (64x64, K=1024),
// softmax(dots*0.125), out = attn @ vv -> O (f16)
// grid: (16 heads, 8 batches), block 512 (8 waves)
// ---------------------------------------------------------------------------
__global__ __launch_bounds__(512) void attn_small(
    const f16* __restrict__ UW2, const f16* __restrict__ WqkvT,
    f16* __restrict__ O)
{
    __shared__ float dots[64][66];
    __shared__ float vv[64][66];
    const int h = blockIdx.x, b = blockIdx.y;
    const int tid = threadIdx.x, lane = tid & 63, w = tid >> 6;
    const int isVV = w >> 2;
    const int kq = w & 3;

    const f16* Arows = UW2 + (size_t)b * (2048 * 1024)
                           + (size_t)isVV * (1024 * 1024) + (size_t)h * 64 * 1024;
    const f16* Brows = WqkvT + (size_t)(isVV ? 3072 : 1024) * 1024 + (size_t)h * 64 * 1024;

    f32x4 acc[4][4];
#pragma unroll
    for (int i = 0; i < 4; ++i)
#pragma unroll
        for (int j = 0; j < 4; ++j) acc[i][j] = f32x4{0.f, 0.f, 0.f, 0.f};

    const int cl = lane & 15, kg = lane >> 4;
    for (int ks = 0; ks < 8; ++ks) {
        const int k0 = kq * 256 + ks * 32 + kg * 8;
        f16x8 af[4], bfr[4];
#pragma unroll
        for (int i = 0; i < 4; ++i)
            af[i] = *(const f16x8*)(Arows + (size_t)(i * 16 + cl) * 1024 + k0);
#pragma unroll
        for (int j = 0; j < 4; ++j)
            bfr[j] = *(const f16x8*)(Brows + (size_t)(j * 16 + cl) * 1024 + k0);
#pragma unroll
        for (int i = 0; i < 4; ++i)
#pragma unroll
            for (int j = 0; j < 4; ++j)
                acc[i][j] = __builtin_amdgcn_mfma_f32_16x16x32_f16(af[i], bfr[j], acc[i][j], 0, 0, 0);
    }

    float (*dst)[66] = isVV ? vv : dots;
#pragma unroll
    for (int r = 0; r < 4; ++r) {
        if (kq == r) {
            if (r == 0) {
#pragma unroll
                for (int i = 0; i < 4; ++i)
#pragma unroll
                    for (int j = 0; j < 4; ++j)
#pragma unroll
                        for (int q = 0; q < 4; ++q)
                            dst[i * 16 + kg * 4 + q][j * 16 + cl] = acc[i][j][q];
            } else {
#pragma unroll
                for (int i = 0; i < 4; ++i)
#pragma unroll
                    for (int j = 0; j < 4; ++j)
#pragma unroll
                        for (int q = 0; q < 4; ++q)
                            dst[i * 16 + kg * 4 + q][j * 16 + cl] += acc[i][j][q];
            }
        }
        __syncthreads();
    }

    if (tid < 64) {
        const int r = tid;
        float mx = -1e30f;
        for (int e = 0; e < 64; ++e) {
            const float v = dots[r][e] * 0.125f;
            dots[r][e] = v;
            mx = fmaxf(mx, v);
        }
        float s = 0.f;
        for (int e = 0; e < 64; ++e) {
            const float v = __expf(dots[r][e] - mx);
            dots[r][e] = v;
            s += v;
        }
        const float inv = 1.f / s;
        for (int e = 0; e < 64; ++e) dots[r][e] *= inv;
    }
    __syncthreads();

    {
        const int r = tid >> 3, f0 = (tid & 7) * 8;
        float o[8];
#pragma unroll
        for (int i = 0; i < 8; ++i) o[i] = 0.f;
        for (int e = 0; e < 64; ++e) {
            const float a = dots[r][e];
#pragma unroll
            for (int i = 0; i < 8; ++i) o[i] += a * vv[e][f0 + i];
        }
        f16* Od = O + (size_t)b * 64 * 1024 + (size_t)r * 1024 + h * 64 + f0;
#pragma unroll
        for (int i = 0; i < 8; ++i) Od[i] = (f16)o[i];
    }
}

// ---------------------------------------------------------------------------
extern "C" void kernel_launch(void* const* d_in, const int* in_sizes, int n_in,
                              void* d_out, int out_size, void* d_ws, size_t ws_size,
                              hipStream_t stream)
{
    const float* x    = (const float*)d_in[0];  // [8][4096][1024]
    const float* Wqkv = (const float*)d_in[1];  // [1024][4096]
    const float* Wout = (const float*)d_in[2];  // [1024][1024]
    const float* bout = (const float*)d_in[3];  // [1024]

    char* ws = (char*)d_ws;
    f16* xT    = (f16*)(ws + 0);           // [8][1024][4096]   67108864 B
    f16* WqkvT = (f16*)(ws + 67108864);    // [4096][1024]       8388608 B
    f16* WoutT = (f16*)(ws + 75497472);    // [1024][1024]       2097152 B
    f16* G     = (f16*)(ws + 77594624);    // [8][1024][1024]   16777216 B
    f16* Gp    = (f16*)(ws + 94371840);    // [2][8][1024][1024] 33554432 B
    f16* UW2   = (f16*)(ws + 94371840);    // union w/ Gp (qv runs after reduce)
    f16* O     = (f16*)(ws + 127926272);   // [8][64][1024]      1048576 B

    tr_cvt_kernel<<<dim3(16, 64, 8), 256, 0, stream>>>(x, xT, 4096, 1024);
    tr_cvt_kernel<<<dim3(64, 16, 1), 256, 0, stream>>>(Wqkv, WqkvT, 1024, 4096);
    tr_cvt_kernel<<<dim3(16, 16, 1), 256, 0, stream>>>(Wout, WoutT, 1024, 1024);

    // K1: full-G split-K=2, 256^2 tiles, single-barrier pipelined
    gemm_syk256<<<256, 512, 0, stream>>>(xT, Gp);
    // G = Gp0 + Gp1
    reduce_sum<<<4096, 256, 0, stream>>>(Gp, G);
    // K2 fused: UW2 = [Wq^T G ; Wv^T G]
    gemm_qv256<<<256, 512, 0, stream>>>(WqkvT, G, UW2);
    // K3: per (b,h) small attention
    attn_small<<<dim3(16, 8), 512, 0, stream>>>(UW2, WqkvT, O);
    // K4: out = O @ WoutT^T + bias (single kernel, no atomics)
    gemm_out<<<dim3(8, 4), 256, 0, stream>>>(O, WoutT, bout, (float*)d_out);
}